// Round 1
// baseline (350.448 us; speedup 1.0000x reference)
//
#include <hip/hip_runtime.h>

#define N_ROWS 524288
#define W_BINS 101
#define EPS_F 1e-3f

// Zero the 3 double accumulators in workspace (ws is re-poisoned to 0xAA
// before every timed launch, so this must run every call).
__global__ __launch_bounds__(64) void init_acc(double* __restrict__ acc) {
    if (threadIdx.x < 3) acc[threadIdx.x] = 0.0;
}

// 16 lanes per row; 4 rows per wave; 4 waves per block (256 threads).
// grid = 2048 blocks -> 32768 groups -> 16 rows per group.
__global__ __launch_bounds__(256) void mrl_main(const float* __restrict__ x,
                                                const int* __restrict__ tgt,
                                                double* __restrict__ acc) {
    const int lane = threadIdx.x & 63;
    const int s    = threadIdx.x & 15;                       // sublane in 16-lane group
    const int gid  = (blockIdx.x * 256 + threadIdx.x) >> 4;  // global group id
    const int totalGroups = (gridDim.x * 256) >> 4;

    float racc = 0.0f;   // residue partial (linear across rows -> deferred reduce)
    float sqac = 0.0f;   // (mean - t)^2 partial (only sublane 0 accumulates)
    int   kacc = 0;      // count of bins with p >= prob_gt

    for (int row = gid; row < N_ROWS; row += totalGroups) {
        const float* xr = x + (size_t)row * W_BINS;

        // Strided load: lane s holds bins s, s+16, ..., s+96(partial).
        // No max-subtraction: |x| small (std normal), exp() safe in fp32.
        float e[6];
        float se = 0.0f, sea = 0.0f;
        #pragma unroll
        for (int k = 0; k < 6; ++k) {
            float v  = xr[s + 16 * k];
            float ev = __expf(v);
            e[k] = ev;
            se  += ev;
            sea += ev * (float)(s + 16 * k);
        }
        float e6 = 0.0f;
        if (s < 5) {                 // bins 96..100
            float v = xr[96 + s];
            e6  = __expf(v);
            se += e6;
            sea += e6 * (float)(96 + s);
        }

        // Reduce sum(e) and sum(e*a) within the 16-lane group (4 steps).
        #pragma unroll
        for (int off = 8; off >= 1; off >>= 1) {
            se  += __shfl_xor(se,  off);
            sea += __shfl_xor(sea, off);
        }

        const int   t    = tgt[row];
        const float inv  = 1.0f / se;
        const float mean = sea * inv;

        // Gather e at the target bin: owner sublane = t & 15, slot = t >> 4.
        const int kq = t >> 4;       // group-uniform
        float cand = e[0];
        if (kq == 1) cand = e[1];
        if (kq == 2) cand = e[2];
        if (kq == 3) cand = e[3];
        if (kq == 4) cand = e[4];
        if (kq == 5) cand = e[5];
        if (kq == 6) cand = e6;
        const float egt = __shfl(cand, (lane & 48) | (t & 15));
        const float pgt = egt * inv;

        if (s == 0) {
            float d = mean - (float)t;
            sqac += d * d;
        }

        // Residue + K over this lane's bins. Masked-out bins (p >= pgt)
        // still contribute -(EPS)*log(EPS), matching the reference.
        #pragma unroll
        for (int k = 0; k < 6; ++k) {
            float p  = e[k] * inv;
            bool  lt = p < pgt;
            float qe = (lt ? p : 0.0f) + EPS_F;
            racc -= qe * __logf(qe);
            kacc += lt ? 0 : 1;
        }
        if (s < 5) {
            float p  = e6 * inv;
            bool  lt = p < pgt;
            float qe = (lt ? p : 0.0f) + EPS_F;
            racc -= qe * __logf(qe);
            kacc += lt ? 0 : 1;
        }
    }

    // Wave-level butterfly over the deferred accumulators (once per wave).
    float kf = (float)kacc;   // <= 112 per lane: exact in float
    #pragma unroll
    for (int off = 32; off >= 1; off >>= 1) {
        racc += __shfl_xor(racc, off);
        sqac += __shfl_xor(sqac, off);
        kf   += __shfl_xor(kf,   off);
    }

    __shared__ float sr[4], ss[4], sk[4];
    const int wid = threadIdx.x >> 6;
    if (lane == 0) { sr[wid] = racc; ss[wid] = sqac; sk[wid] = kf; }
    __syncthreads();
    if (threadIdx.x == 0) {
        double S = (double)ss[0] + (double)ss[1] + (double)ss[2] + (double)ss[3];
        double R = (double)sr[0] + (double)sr[1] + (double)sr[2] + (double)sr[3];
        double K = (double)sk[0] + (double)sk[1] + (double)sk[2] + (double)sk[3];
        atomicAdd(&acc[0], S);
        atomicAdd(&acc[1], R);
        atomicAdd(&acc[2], K);
    }
}

__global__ __launch_bounds__(64) void finalize(const double* __restrict__ acc,
                                               float* __restrict__ out) {
    if (threadIdx.x == 0) {
        const double n = (double)N_ROWS;
        out[0] = (float)(0.2  * 0.5 * (acc[0] / n));  // LAMBDA_1 * mean_loss
        out[1] = (float)(0.05 *       (acc[1] / n));  // LAMBDA_2 * residue_loss
        out[2] = (float)(acc[2] / n);                 // batch_average_K
    }
}

extern "C" void kernel_launch(void* const* d_in, const int* in_sizes, int n_in,
                              void* d_out, int out_size, void* d_ws, size_t ws_size,
                              hipStream_t stream) {
    const float* x   = (const float*)d_in[0];
    const int*   tgt = (const int*)d_in[1];
    float*  out = (float*)d_out;
    double* acc = (double*)d_ws;

    init_acc<<<1, 64, 0, stream>>>(acc);
    mrl_main<<<2048, 256, 0, stream>>>(x, tgt, acc);
    finalize<<<1, 64, 0, stream>>>(acc, out);
}

// Round 2
// 334.241 us; speedup vs baseline: 1.0485x; 1.0485x over previous
//
#include <hip/hip_runtime.h>

#define N_ROWS 524288
#define W_BINS 101
#define EPS_F 1e-3f

// Zero the 3 double accumulators in workspace (ws is re-poisoned to 0xAA
// before every timed launch, so this must run every call).
__global__ __launch_bounds__(64) void init_acc(double* __restrict__ acc) {
    if (threadIdx.x < 3) acc[threadIdx.x] = 0.0;
}

// 16 lanes per row; 4 rows per wave; 4 waves per block (256 threads).
// grid = 2048 blocks -> 32768 groups -> 16 rows per group, processed
// TWO AT A TIME (8 iterations) so two independent dependency chains
// overlap (round-1 showed VALUBusy 32%, HBM 9% -> latency-bound,
// VGPR=28 -> compiler kept only one row in flight).
__global__ __launch_bounds__(256) void mrl_main(const float* __restrict__ x,
                                                const int* __restrict__ tgt,
                                                double* __restrict__ acc) {
    const int lane = threadIdx.x & 63;
    const int s    = threadIdx.x & 15;                       // sublane in 16-lane group
    const int gid  = (blockIdx.x * 256 + threadIdx.x) >> 4;  // global group id
    const int G    = (gridDim.x * 256) >> 4;                 // total groups (32768)

    float racc = 0.0f;   // residue partial
    float sqac = 0.0f;   // (mean - t)^2 partial (sublane 0 only)
    int   kacc = 0;      // count of bins with p >= prob_gt

    // N_ROWS / G = 16 rows per group exactly; stride-2G loop = 8 iters.
    for (int rowA = gid; rowA < N_ROWS; rowA += 2 * G) {
        const int rowB = rowA + G;
        const float* xa = x + (size_t)rowA * W_BINS;
        const float* xb = x + (size_t)rowB * W_BINS;

        const int ta = tgt[rowA];
        const int tb = tgt[rowB];
        // Direct broadcast load of the target logit (replaces the
        // cndmask-select + shfl gather of round 1).
        const float xta = xa[ta];
        const float xtb = xb[tb];

        float ea[7], eb[7];
        float seA = 0.f, seaA = 0.f, seB = 0.f, seaB = 0.f;
        #pragma unroll
        for (int k = 0; k < 6; ++k) {
            const float c  = (float)(s + 16 * k);
            float va = xa[s + 16 * k];
            float vb = xb[s + 16 * k];
            float Ea = __expf(va);
            float Eb = __expf(vb);
            ea[k] = Ea; eb[k] = Eb;
            seA += Ea; seaA += Ea * c;
            seB += Eb; seaB += Eb * c;
        }
        ea[6] = 0.f; eb[6] = 0.f;
        if (s < 5) {                 // bins 96..100
            const float c = (float)(96 + s);
            float Ea = __expf(xa[96 + s]);
            float Eb = __expf(xb[96 + s]);
            ea[6] = Ea; eb[6] = Eb;
            seA += Ea; seaA += Ea * c;
            seB += Eb; seaB += Eb * c;
        }

        // 16-lane butterfly for sum(e), sum(e*a) of both rows (chains interleave).
        #pragma unroll
        for (int off = 8; off >= 1; off >>= 1) {
            seA  += __shfl_xor(seA,  off);
            seaA += __shfl_xor(seaA, off);
            seB  += __shfl_xor(seB,  off);
            seaB += __shfl_xor(seaB, off);
        }

        const float egta = __expf(xta);
        const float egtb = __expf(xtb);
        const float invA = __builtin_amdgcn_rcpf(seA);
        const float invB = __builtin_amdgcn_rcpf(seB);

        if (s == 0) {
            float dA = seaA * invA - (float)ta;
            float dB = seaB * invB - (float)tb;
            sqac += dA * dA + dB * dB;
        }

        // Residue + K. Mask compare done in e-space (scale-invariant):
        // e_i < e_gt  <=>  p_i < p_gt. Masked-out bins contribute
        // -(EPS)*log(EPS), matching the reference.
        #pragma unroll
        for (int k = 0; k < 7; ++k) {
            bool  ltA = ea[k] < egta;
            bool  ltB = eb[k] < egtb;
            float qA  = (ltA ? ea[k] * invA : 0.0f) + EPS_F;
            float qB  = (ltB ? eb[k] * invB : 0.0f) + EPS_F;
            racc -= qA * __logf(qA);
            racc -= qB * __logf(qB);
            // k==6 lanes s>=5 hold e=0 which must not count as a bin at all:
            // e=0 < egt always true there, so it adds -(EPS)log(EPS); subtract
            // that constant contribution back out below via the fixup.
            kacc += (ltA ? 0 : 1) + (ltB ? 0 : 1);
        }
        // Fixup: lanes s>=5 processed a phantom bin (k==6, e==0) for each of
        // the 2 rows: each added -(EPS)*log(EPS) to racc and 0 to kacc.
        if (s >= 5) {
            const float phantom = -EPS_F * __logf(EPS_F);
            racc -= 2.0f * phantom;
        }
    }

    // Wave-level butterfly over the deferred accumulators (once per wave).
    float kf = (float)kacc;   // <= 224 per lane: exact in float
    #pragma unroll
    for (int off = 32; off >= 1; off >>= 1) {
        racc += __shfl_xor(racc, off);
        sqac += __shfl_xor(sqac, off);
        kf   += __shfl_xor(kf,   off);
    }

    __shared__ float sr[4], ss[4], sk[4];
    const int wid = threadIdx.x >> 6;
    if (lane == 0) { sr[wid] = racc; ss[wid] = sqac; sk[wid] = kf; }
    __syncthreads();
    if (threadIdx.x == 0) {
        double S = (double)ss[0] + (double)ss[1] + (double)ss[2] + (double)ss[3];
        double R = (double)sr[0] + (double)sr[1] + (double)sr[2] + (double)sr[3];
        double K = (double)sk[0] + (double)sk[1] + (double)sk[2] + (double)sk[3];
        atomicAdd(&acc[0], S);
        atomicAdd(&acc[1], R);
        atomicAdd(&acc[2], K);
    }
}

__global__ __launch_bounds__(64) void finalize(const double* __restrict__ acc,
                                               float* __restrict__ out) {
    if (threadIdx.x == 0) {
        const double n = (double)N_ROWS;
        out[0] = (float)(0.2  * 0.5 * (acc[0] / n));  // LAMBDA_1 * mean_loss
        out[1] = (float)(0.05 *       (acc[1] / n));  // LAMBDA_2 * residue_loss
        out[2] = (float)(acc[2] / n);                 // batch_average_K
    }
}

extern "C" void kernel_launch(void* const* d_in, const int* in_sizes, int n_in,
                              void* d_out, int out_size, void* d_ws, size_t ws_size,
                              hipStream_t stream) {
    const float* x   = (const float*)d_in[0];
    const int*   tgt = (const int*)d_in[1];
    float*  out = (float*)d_out;
    double* acc = (double*)d_ws;

    init_acc<<<1, 64, 0, stream>>>(acc);
    mrl_main<<<2048, 256, 0, stream>>>(x, tgt, acc);
    finalize<<<1, 64, 0, stream>>>(acc, out);
}

// Round 3
// 302.640 us; speedup vs baseline: 1.1580x; 1.1044x over previous
//
#include <hip/hip_runtime.h>

#define N_ROWS   524288
#define W_BINS   101
#define EPS_F    1e-3f
#define RPB      64                    // rows per block = 1 row per lane
#define NBLK     (N_ROWS / RPB)        // 8192 blocks
#define TILE_F   (RPB * W_BINS)        // 6464 floats per tile (25,856 B LDS)

typedef const float __attribute__((address_space(1)))* gptr_t;
typedef float __attribute__((address_space(3)))* sptr_t;

// One block = one 64-row tile. DMA the tile into LDS (contiguous, coalesced),
// then each lane computes one full row with zero cross-lane traffic until the
// final 3-scalar butterfly. No atomics: per-block partials to ws.
__global__ __launch_bounds__(64) void mrl_main(const float* __restrict__ x,
                                               const int* __restrict__ tgt,
                                               float4* __restrict__ partial) {
    __shared__ float sm[TILE_F];
    const int lane = threadIdx.x;                       // 0..63
    const float* gbase = x + (size_t)blockIdx.x * TILE_F;

    // Async global->LDS DMA: 16 B/lane/instr = 1 KiB/instr. 6464 floats =
    // 25 full instrs + one 16-lane tail. LDS dest is wave-uniform base +
    // lane*16 == exactly our linear layout.
    #pragma unroll
    for (int q = 0; q < 25; ++q) {
        __builtin_amdgcn_global_load_lds((gptr_t)(gbase + q * 256 + lane * 4),
                                         (sptr_t)(sm + q * 256), 16, 0, 0);
    }
    if (lane < 16) {
        __builtin_amdgcn_global_load_lds((gptr_t)(gbase + 6400 + lane * 4),
                                         (sptr_t)(sm + 6400), 16, 0, 0);
    }

    const int row = blockIdx.x * RPB + lane;
    const int t   = tgt[row];            // coalesced; issued before the drain

    __syncthreads();                     // drains vmcnt -> DMA deposits visible

    const float* r = sm + lane * W_BINS; // lane-stride 101 words: 2-way banks = free

    // Pass 1: sum(e), sum(e*a). No max-subtraction: inputs are std-normal,
    // exp() safe in fp32. Two accumulators break the serial add chain.
    float se0 = 0.f, se1 = 0.f, sa0 = 0.f, sa1 = 0.f;
    #pragma unroll
    for (int i = 0; i < 100; i += 2) {
        float e0 = __expf(r[i]);
        float e1 = __expf(r[i + 1]);
        se0 += e0; sa0 += e0 * (float)i;
        se1 += e1; sa1 += e1 * (float)(i + 1);
    }
    {
        float e = __expf(r[100]);
        se0 += e; sa0 += e * 100.0f;
    }
    const float se  = se0 + se1;
    const float sea = sa0 + sa1;

    const float egt = __expf(r[t]);      // gather: random bank, single instr
    const float inv = __builtin_amdgcn_rcpf(se);
    const float d   = sea * inv - (float)t;
    float sq = d * d;

    // Pass 2: residue + K. Compare in e-space (scale-invariant):
    // e_i < e_gt  <=>  p_i < p_gt. Masked-out bins contribute -(EPS)log(EPS),
    // matching the reference. i==t gives e==egt -> not lt -> counted in K.
    float rc0 = 0.f, rc1 = 0.f;
    int   k   = 0;
    #pragma unroll
    for (int i = 0; i < 100; i += 2) {
        float e0 = __expf(r[i]);
        float e1 = __expf(r[i + 1]);
        bool  l0 = e0 < egt, l1 = e1 < egt;
        float q0 = (l0 ? e0 * inv : 0.f) + EPS_F;
        float q1 = (l1 ? e1 * inv : 0.f) + EPS_F;
        rc0 -= q0 * __logf(q0);
        rc1 -= q1 * __logf(q1);
        k   += (l0 ? 0 : 1) + (l1 ? 0 : 1);
    }
    {
        float e = __expf(r[100]);
        bool  l = e < egt;
        float q = (l ? e * inv : 0.f) + EPS_F;
        rc0 -= q * __logf(q);
        k   += l ? 0 : 1;
    }
    float rc = rc0 + rc1;
    float kf = (float)k;                 // <= 101, exact in float

    // Wave butterfly over the 3 per-row scalars.
    #pragma unroll
    for (int off = 32; off >= 1; off >>= 1) {
        sq += __shfl_xor(sq, off);
        rc += __shfl_xor(rc, off);
        kf += __shfl_xor(kf, off);
    }
    if (lane == 0) {
        partial[blockIdx.x] = make_float4(sq, rc, kf, 0.0f);
    }
}

__global__ __launch_bounds__(256) void mrl_reduce(const float4* __restrict__ partial,
                                                  float* __restrict__ out) {
    double s = 0.0, r = 0.0, k = 0.0;
    for (int i = threadIdx.x; i < NBLK; i += 256) {
        float4 v = partial[i];
        s += (double)v.x; r += (double)v.y; k += (double)v.z;
    }
    #pragma unroll
    for (int off = 32; off >= 1; off >>= 1) {
        s += __shfl_xor(s, off);
        r += __shfl_xor(r, off);
        k += __shfl_xor(k, off);
    }
    __shared__ double sd[12];
    const int w = threadIdx.x >> 6;
    if ((threadIdx.x & 63) == 0) { sd[w * 3 + 0] = s; sd[w * 3 + 1] = r; sd[w * 3 + 2] = k; }
    __syncthreads();
    if (threadIdx.x == 0) {
        double S = sd[0] + sd[3] + sd[6] + sd[9];
        double R = sd[1] + sd[4] + sd[7] + sd[10];
        double K = sd[2] + sd[5] + sd[8] + sd[11];
        const double n = (double)N_ROWS;
        out[0] = (float)(0.1  * (S / n));   // LAMBDA_1 * mean_loss (0.2 * 0.5)
        out[1] = (float)(0.05 * (R / n));   // LAMBDA_2 * residue_loss
        out[2] = (float)(K / n);            // batch_average_K
    }
}

extern "C" void kernel_launch(void* const* d_in, const int* in_sizes, int n_in,
                              void* d_out, int out_size, void* d_ws, size_t ws_size,
                              hipStream_t stream) {
    const float* x   = (const float*)d_in[0];
    const int*   tgt = (const int*)d_in[1];
    float*  out     = (float*)d_out;
    float4* partial = (float4*)d_ws;    // 8192 * 16 B = 128 KiB, well under ws_size

    mrl_main<<<NBLK, RPB, 0, stream>>>(x, tgt, partial);
    mrl_reduce<<<1, 256, 0, stream>>>(partial, out);
}